// Round 3
// baseline (618.754 us; speedup 1.0000x reference)
//
#include <hip/hip_runtime.h>
#include <hip/hip_bf16.h>
#include <hip/hip_fp16.h>
#include <cstdint>
#include <cstddef>

#define H 96
#define W 96
#define HW 9216
#define C 256
#define B 8
#define O 256
#define KK 9
#define EPS 1e-5f

typedef __attribute__((ext_vector_type(8))) short short8;
typedef __attribute__((ext_vector_type(4))) float float4v;
typedef __attribute__((ext_vector_type(2))) float float2v;
typedef unsigned short ushort_t;
typedef unsigned int uint_t;

// ---------------- Kernel 1: transpose x (B,C,HW) fp32 -> x_t (B,HW,C) bf16
__global__ __launch_bounds__(256) void transpose_x_k(
    const float* __restrict__ x, ushort_t* __restrict__ xt)
{
    __shared__ float tile[64][65];
    int t = threadIdx.x;
    int p0 = blockIdx.x * 64;
    int c0 = blockIdx.y * 64;
    int b  = blockIdx.z;
    {
        int tx = t & 63, ty = t >> 6;
        const float* xb = x + ((size_t)b * C + c0 + ty) * HW + p0 + tx;
#pragma unroll
        for (int i = 0; i < 64; i += 4)
            tile[ty + i][tx] = xb[(size_t)i * HW];
    }
    __syncthreads();
    {
        int tc = t & 31, tp = t >> 5;
        ushort_t* xtb = xt + ((size_t)b * HW + p0) * C + c0;
#pragma unroll
        for (int i = 0; i < 64; i += 8) {
            int p = tp + i;
            float a  = tile[2 * tc][p];
            float bb = tile[2 * tc + 1][p];
            __hip_bfloat162 h2 = __float22bfloat162_rn(make_float2(a, bb));
            uint_t u;
            __builtin_memcpy(&u, &h2, 4);
            *reinterpret_cast<uint_t*>(&xtb[(size_t)p * C + 2 * tc]) = u;
        }
    }
}

// ---------------- Kernel 2: w_dcn (O, C, KK) fp32 -> Bp[kk][o][c] bf16
__global__ __launch_bounds__(256) void prep_b_k(
    const float* __restrict__ wd, ushort_t* __restrict__ bp)
{
    int idx = blockIdx.x * 256 + threadIdx.x;
    int kk = idx / (O * C);
    int r = idx - kk * O * C;
    int o = r >> 8, c = r & 255;
    float v = wd[((size_t)o * C + c) * KK + kk];
    __hip_bfloat16 hh = __float2bfloat16(v);
    ushort_t u;
    __builtin_memcpy(&u, &hh, 2);
    bp[idx] = u;
}

// ---------------- Kernel 3: w_off (27, C, 3, 3) fp32 -> bo[n=32][kk][c] bf16
__global__ __launch_bounds__(256) void prep_bo_k(
    const float* __restrict__ wo, ushort_t* __restrict__ bo)
{
    int idx = blockIdx.x * 256 + threadIdx.x;
    int n = idx / (KK * C);
    int r = idx - n * KK * C;
    int kk = r >> 8, c = r & 255;
    float v = (n < 27) ? wo[((size_t)n * C + c) * KK + kk] : 0.0f;
    __hip_bfloat16 hh = __float2bfloat16(v);
    ushort_t u;
    __builtin_memcpy(&u, &hh, 2);
    bo[idx] = u;
}

// ---------------- Kernel 4: offset conv via MFMA (XCD-swizzled, branch-free loads)
__global__ __launch_bounds__(256) void offset_mfma_k(
    const ushort_t* __restrict__ xt, const ushort_t* __restrict__ bo,
    const float* __restrict__ b_off, float* __restrict__ om)
{
    int t = threadIdx.x;
    int wv = t >> 6, l = t & 63;
    int ln = l & 15, lq = l >> 4;
    int d = blockIdx.x;                      // 576 = 8 XCD * 72 (one batch each)
    int lb = (d & 7) * 72 + (d >> 3);
    int p0 = lb * 128;
    int b = p0 / HW;
    int rem0w = p0 - b * HW + wv * 32;
    const ushort_t* xtb = xt + (size_t)b * HW * C;

    int hh0[2], ww0[2];
#pragma unroll
    for (int mt = 0; mt < 2; ++mt) {
        int rem = rem0w + mt * 16 + ln;
        hh0[mt] = rem / W;
        ww0[mt] = rem - hh0[mt] * W;
    }

    float4v acc[2][2];
#pragma unroll
    for (int i = 0; i < 2; ++i)
#pragma unroll
        for (int j = 0; j < 2; ++j) acc[i][j] = (float4v){0.f, 0.f, 0.f, 0.f};

#pragma unroll
    for (int kk = 0; kk < KK; ++kk) {
        int dy = kk / 3 - 1, dx = kk % 3 - 1;
        const ushort_t* ap[2];
        uint_t msk[2];
#pragma unroll
        for (int mt = 0; mt < 2; ++mt) {
            int hh = hh0[mt] + dy, ww = ww0[mt] + dx;
            bool ok = (hh >= 0) & (hh < H) & (ww >= 0) & (ww < W);
            msk[mt] = ok ? 0xffffffffu : 0u;
            int hc = min(max(hh, 0), H - 1);
            int wc = min(max(ww, 0), W - 1);
            ap[mt] = xtb + (size_t)(hc * W + wc) * C + lq * 8;
        }
        const ushort_t* bp0 = bo + ((size_t)(0 * 16 + ln) * KK + kk) * C + lq * 8;
        const ushort_t* bp1 = bo + ((size_t)(1 * 16 + ln) * KK + kk) * C + lq * 8;
#pragma unroll
        for (int cc = 0; cc < 8; ++cc) {
            int c0 = cc * 32;
            short8 af[2];
#pragma unroll
            for (int mt = 0; mt < 2; ++mt) {
                uint4 u = *(const uint4*)(ap[mt] + c0);
                u.x &= msk[mt]; u.y &= msk[mt]; u.z &= msk[mt]; u.w &= msk[mt];
                __builtin_memcpy(&af[mt], &u, 16);
            }
            short8 bf0 = *(const short8*)(bp0 + c0);
            short8 bf1 = *(const short8*)(bp1 + c0);
#pragma unroll
            for (int mt = 0; mt < 2; ++mt) {
                acc[mt][0] = __builtin_amdgcn_mfma_f32_16x16x32_bf16(af[mt], bf0, acc[mt][0], 0, 0, 0);
                acc[mt][1] = __builtin_amdgcn_mfma_f32_16x16x32_bf16(af[mt], bf1, acc[mt][1], 0, 0, 0);
            }
        }
    }

    float* omb = om + (size_t)b * 27 * HW + rem0w;
#pragma unroll
    for (int nt = 0; nt < 2; ++nt) {
        int oc = nt * 16 + ln;
        if (oc < 27) {
            float bv = b_off[oc];
            float* po = omb + (size_t)oc * HW + lq * 4;
#pragma unroll
            for (int mt = 0; mt < 2; ++mt) {
                float4 v;
                v.x = acc[mt][nt].x + bv;
                v.y = acc[mt][nt].y + bv;
                v.z = acc[mt][nt].z + bv;
                v.w = acc[mt][nt].w + bv;
                *(float4*)(po + mt * 16) = v;
            }
        }
    }
}

__device__ __forceinline__ float2v up2(uint_t u) {
    float2v r;
    r.x = __uint_as_float(u << 16);
    r.y = __uint_as_float(u & 0xffff0000u);
    return r;
}

__device__ __forceinline__ uint_t packbf2(float a, float b) {
    __hip_bfloat162 h2 = __float22bfloat162_rn(make_float2(a, b));
    uint_t u;
    __builtin_memcpy(&u, &h2, 4);
    return u;
}

// ---------------- Kernel 5: deformable conv main
// 512 threads = 8 waves: pixel-half (mh = t>>8) x output-quarter (nq = (t>>6)&3).
// Each wave: acc[2][4] = 32 px x 64 outs. A-tile LDS reads/phase unchanged vs
// 4-wave version (8 waves x 2 = 4 x 4); B-reads double but B is 1.2 MB L1/L2-hot.
// 18 half-phases (tap = ph>>1, channel-half hf = ph&1, 128 ch each).
// dbuf 2x16KB + 12B records -> LDS 39680B. Worst-case VGPR<=128 still gives
// 2 blocks = 16 waves/CU (50% occ); goal 3 blocks = 24 waves (75%).
// Round-1 lesson: NO min-waves arg (VGPR quantizes to 64 -> 1.3GB spills).
// Round-2 lesson: 256-thread blocks never exceeded ~2-block residency (19% occ);
// waves-per-block is the reliable occupancy lever, not blocks-per-CU.
__global__ __launch_bounds__(512) void dcn_main_k(
    const ushort_t* __restrict__ xt, const float* __restrict__ om,
    const ushort_t* __restrict__ bp, const float* __restrict__ b_dcn,
    const float* __restrict__ gamma, const float* __restrict__ beta,
    const float* __restrict__ rmean, const float* __restrict__ rvar,
    float* __restrict__ out)
{
    // rec: .x = px0 | (px1<<16)  (pixel indices, <HW fits 14 bits)
    //      .y = half2(row0f, row1f)   .z = half2(wA, wB)   (rank-1 weights)
    __shared__ uint3    s_rec[64 * KK];          // 6912B
    __shared__ ushort_t s_a[2][4][64][32];       // [buf][ci][m][c]  32768B

    int t = threadIdx.x;
    int d = blockIdx.x;                          // 1152 = 8 XCD * 144
    int lb = (d & 7) * 144 + (d >> 3);
    int p0 = lb * 64;
    int b = p0 / HW;
    int rem0 = p0 - b * HW;

    // ---- bilinear records, indexed [kk*64 + m]
    for (int v = t; v < 64 * KK; v += 512) {
        int m = v & 63;
        int k = v >> 6;
        int rem = rem0 + m;
        int h = rem / W;
        int w = rem - h * W;
        const float* omb = om + (size_t)b * 27 * HW + rem;
        float offy = omb[(size_t)(2 * k) * HW];
        float offx = omb[(size_t)(2 * k + 1) * HW];
        float z    = omb[(size_t)(18 + k) * HW];
        float mval = 1.0f / (1.0f + __expf(-z));
        float py = (float)(h + k / 3 - 1) + offy;
        float px = (float)(w + k % 3 - 1) + offx;
        float fy = floorf(py), fx = floorf(px);
        int y0 = (int)fy, x0 = (int)fx;
        float wy = py - fy, wx = px - fx;
        float row0f = (1.0f - wy) * mval * ((y0 >= 0 && y0 < H) ? 1.0f : 0.0f);
        float row1f = wy * mval * ((y0 >= -1 && y0 < H - 1) ? 1.0f : 0.0f);
        int xsel = min(max(x0, 0), W - 2);
        float wxa = (x0 >= 0 && x0 < W) ? (1.0f - wx) : 0.0f;
        float wxb = (x0 >= -1 && x0 < W - 1) ? wx : 0.0f;
        int cx0 = min(max(x0, 0), W - 1);
        int cx1 = min(max(x0 + 1, 0), W - 1);
        float wA = ((cx0 == xsel) ? wxa : 0.0f) + ((cx1 == xsel) ? wxb : 0.0f);
        float wB = ((cx0 == xsel + 1) ? wxa : 0.0f) + ((cx1 == xsel + 1) ? wxb : 0.0f);
        int yc0 = min(max(y0, 0), H - 1);
        int yc1 = min(max(y0 + 1, 0), H - 1);
        uint3 rr;
        rr.x = (uint_t)(yc0 * W + xsel) | ((uint_t)(yc1 * W + xsel) << 16);
        __half2 h01 = __floats2half2_rn(row0f, row1f);
        __half2 hAB = __floats2half2_rn(wA, wB);
        __builtin_memcpy(&rr.y, &h01, 4);
        __builtin_memcpy(&rr.z, &hAB, 4);
        s_rec[v] = rr;
    }

    float4v acc[2][4];
#pragma unroll
    for (int i = 0; i < 2; ++i)
#pragma unroll
        for (int j = 0; j < 4; ++j)
            acc[i][j] = (float4v){0.f, 0.f, 0.f, 0.f};

    const ushort_t* xtb = xt + (size_t)b * HW * C;
    int l  = t & 63;
    int ln = l & 15;
    int lq = l >> 4;
    int nq = (t >> 6) & 3;    // output quarter (o base = nq*64)
    int mh = t >> 8;          // pixel half (m base = mh*32)
    int sm = t >> 3;          // staging pixel 0..63
    int sc = (t & 7) * 8;     // staging channel octet within 64-ch group
    int cs0 = (t >> 2) & 1;   // chunk parity from octet group (sc/32)
    int sco = (t & 3) * 8;    // channel offset within 32-ch chunk

    __syncthreads();

    // decode a 12B record into staging pointers (at channel base cb) + 4 weights
#define DECREC(rr_, cb_, a0_, a1_, Wt_) do {                                \
        int px0_ = (rr_).x & 0xffff;                                        \
        int px1_ = (rr_).x >> 16;                                           \
        (a0_) = xtb + (size_t)px0_ * C + (cb_) + sc;                        \
        (a1_) = xtb + (size_t)px1_ * C + (cb_) + sc;                        \
        __half2 h01_, hAB_;                                                 \
        __builtin_memcpy(&h01_, &(rr_).y, 4);                               \
        __builtin_memcpy(&hAB_, &(rr_).z, 4);                               \
        float r0_ = __low2float(h01_), r1_ = __high2float(h01_);            \
        float wa_ = __low2float(hAB_), wb_ = __high2float(hAB_);            \
        (Wt_)[0] = r0_ * wa_; (Wt_)[1] = r0_ * wb_;                         \
        (Wt_)[2] = r1_ * wa_; (Wt_)[3] = r1_ * wb_;                         \
    } while (0)

    // combine one 8-channel group from 4 corner uint4s -> packed bf16 uint4
#define COMBINE(L0_, L1_, L2_, L3_, W_, dst_) do {                          \
        uint4 pk_;                                                          \
        float2v r0_ = up2((L0_).x) * (W_)[0] + up2((L1_).x) * (W_)[1]       \
                    + up2((L2_).x) * (W_)[2] + up2((L3_).x) * (W_)[3];      \
        float2v r1_ = up2((L0_).y) * (W_)[0] + up2((L1_).y) * (W_)[1]       \
                    + up2((L2_).y) * (W_)[2] + up2((L3_).y) * (W_)[3];      \
        float2v r2_ = up2((L0_).z) * (W_)[0] + up2((L1_).z) * (W_)[1]       \
                    + up2((L2_).z) * (W_)[2] + up2((L3_).z) * (W_)[3];      \
        float2v r3_ = up2((L0_).w) * (W_)[0] + up2((L1_).w) * (W_)[1]       \
                    + up2((L2_).w) * (W_)[2] + up2((L3_).w) * (W_)[3];      \
        pk_.x = packbf2(r0_.x, r0_.y);                                      \
        pk_.y = packbf2(r1_.x, r1_.y);                                      \
        pk_.z = packbf2(r2_.x, r2_.y);                                      \
        pk_.w = packbf2(r3_.x, r3_.y);                                      \
        *(uint4*)(dst_) = pk_;                                              \
    } while (0)

    // ---- prologue: stage phase 0 (tap 0, channel-half 0) into buf 0
    {
        uint3 rr = s_rec[sm];
        const ushort_t *a0, *a1;
        float Wt[4];
        DECREC(rr, 0, a0, a1, Wt);
#pragma unroll
        for (int cis = 0; cis < 2; ++cis) {
            uint4 L0 = *(const uint4*)(a0 + cis * 64);
            uint4 L1 = *(const uint4*)(a0 + cis * 64 + C);
            uint4 L2 = *(const uint4*)(a1 + cis * 64);
            uint4 L3 = *(const uint4*)(a1 + cis * 64 + C);
            COMBINE(L0, L1, L2, L3, Wt, &s_a[0][cis * 2 + cs0][sm][sco]);
        }
    }
    __syncthreads();

    for (int ph = 0; ph < 2 * KK; ++ph) {
        int rb = ph & 1;
        int wb = rb ^ 1;
        bool more = (ph < 2 * KK - 1);
        int tap = ph >> 1, hf = ph & 1;

        // next-phase staging pointers/weights
        const ushort_t* a0n = xtb;
        const ushort_t* a1n = xtb;
        float Wn[4] = {0.f, 0.f, 0.f, 0.f};
        if (more) {
            int np = ph + 1;
            uint3 rr = s_rec[(np >> 1) * 64 + sm];
            DECREC(rr, (np & 1) * 128, a0n, a1n, Wn);
        }

        const ushort_t* bpk = bp + ((size_t)tap * O + nq * 64 + ln) * C + hf * 128 + lq * 8;

        uint4 L0, L1, L2, L3;
#pragma unroll
        for (int ci = 0; ci < 4; ++ci) {
            // stage-loads for next phase: issue 64-ch group at ci 0/2,
            // combine after the MFMAs of ci 1/3 (one-chunk latency cover,
            // remainder hidden by TLP at 16-24 waves/CU)
            if (more && (ci & 1) == 0) {
                int cis = ci >> 1;
                L0 = *(const uint4*)(a0n + cis * 64);
                L1 = *(const uint4*)(a0n + cis * 64 + C);
                L2 = *(const uint4*)(a1n + cis * 64);
                L3 = *(const uint4*)(a1n + cis * 64 + C);
            }
            // B slices for this chunk (L1/L2-hot, no cross-chunk prefetch)
            short8 bfr[4];
#pragma unroll
            for (int nt = 0; nt < 4; ++nt)
                bfr[nt] = *(const short8*)(bpk + (size_t)nt * 16 * C + ci * 32);
            // MFMA on current buffer, chunk ci
            short8 af[2];
#pragma unroll
            for (int mt = 0; mt < 2; ++mt)
                af[mt] = *(const short8*)&s_a[rb][ci][mh * 32 + mt * 16 + ln][lq * 8];
#pragma unroll
            for (int mt = 0; mt < 2; ++mt)
#pragma unroll
                for (int nt = 0; nt < 4; ++nt)
                    acc[mt][nt] = __builtin_amdgcn_mfma_f32_16x16x32_bf16(
                        af[mt], bfr[nt], acc[mt][nt], 0, 0, 0);
            // combine + publish next-phase chunks
            if (more && (ci & 1) == 1)
                COMBINE(L0, L1, L2, L3, Wn, &s_a[wb][(ci >> 1) * 2 + cs0][sm][sco]);
        }
        __syncthreads();
    }
#undef COMBINE
#undef DECREC

    // ---- epilogue: bias + BN + ReLU
#pragma unroll
    for (int nt = 0; nt < 4; ++nt) {
        int o = nq * 64 + nt * 16 + ln;
        float scale = gamma[o] * rsqrtf(rvar[o] + EPS);
        float shift = (b_dcn[o] - rmean[o]) * scale + beta[o];
        float* po = out + ((size_t)b * O + o) * HW + rem0 + mh * 32 + lq * 4;
#pragma unroll
        for (int mt = 0; mt < 2; ++mt) {
            float4 vv;
            vv.x = fmaxf(acc[mt][nt].x * scale + shift, 0.0f);
            vv.y = fmaxf(acc[mt][nt].y * scale + shift, 0.0f);
            vv.z = fmaxf(acc[mt][nt].z * scale + shift, 0.0f);
            vv.w = fmaxf(acc[mt][nt].w * scale + shift, 0.0f);
            *(float4*)(po + mt * 16) = vv;
        }
    }
}

extern "C" void kernel_launch(void* const* d_in, const int* in_sizes, int n_in,
                              void* d_out, int out_size, void* d_ws, size_t ws_size,
                              hipStream_t stream) {
    const float* x     = (const float*)d_in[0];
    const float* w_off = (const float*)d_in[1];
    const float* b_off = (const float*)d_in[2];
    const float* w_dcn = (const float*)d_in[3];
    const float* b_dcn = (const float*)d_in[4];
    const float* gamma = (const float*)d_in[5];
    const float* beta  = (const float*)d_in[6];
    const float* rmean = (const float*)d_in[7];
    const float* rvar  = (const float*)d_in[8];
    float* out = (float*)d_out;

    float*    om  = (float*)d_ws;                          // 1,990,656 f (7.96 MB)
    ushort_t* bpw = (ushort_t*)(om + (size_t)B * 27 * HW); // 589,824 us (1.18 MB)
    ushort_t* bow = bpw + (size_t)KK * O * C;              // 73,728 us (147 KB)
    ushort_t* xtw = bow + (size_t)32 * KK * C;             // 18,874,368 us (37.7 MB)

    hipLaunchKernelGGL(transpose_x_k, dim3(144, 4, 8), dim3(256), 0, stream,
                       x, xtw);
    hipLaunchKernelGGL(prep_b_k, dim3(2304), dim3(256), 0, stream,
                       w_dcn, bpw);
    hipLaunchKernelGGL(prep_bo_k, dim3(288), dim3(256), 0, stream,
                       w_off, bow);
    hipLaunchKernelGGL(offset_mfma_k, dim3(73728 / 128), dim3(256), 0, stream,
                       xtw, bow, b_off, om);
    hipLaunchKernelGGL(dcn_main_k, dim3(73728 / 64), dim3(512), 0, stream,
                       xtw, om, bpw, b_dcn, gamma, beta, rmean, rvar, out);
}

// Round 4
// 527.133 us; speedup vs baseline: 1.1738x; 1.1738x over previous
//
#include <hip/hip_runtime.h>
#include <hip/hip_bf16.h>
#include <hip/hip_fp16.h>
#include <cstdint>
#include <cstddef>

#define H 96
#define W 96
#define HW 9216
#define C 256
#define B 8
#define O 256
#define KK 9
#define EPS 1e-5f

typedef __attribute__((ext_vector_type(8))) short short8;
typedef __attribute__((ext_vector_type(4))) float float4v;
typedef __attribute__((ext_vector_type(2))) float float2v;
typedef unsigned short ushort_t;
typedef unsigned int uint_t;

// ---------------- Kernel 1: transpose x (B,C,HW) fp32 -> x_t (B,HW,C) bf16
__global__ __launch_bounds__(256) void transpose_x_k(
    const float* __restrict__ x, ushort_t* __restrict__ xt)
{
    __shared__ float tile[64][65];
    int t = threadIdx.x;
    int p0 = blockIdx.x * 64;
    int c0 = blockIdx.y * 64;
    int b  = blockIdx.z;
    {
        int tx = t & 63, ty = t >> 6;
        const float* xb = x + ((size_t)b * C + c0 + ty) * HW + p0 + tx;
#pragma unroll
        for (int i = 0; i < 64; i += 4)
            tile[ty + i][tx] = xb[(size_t)i * HW];
    }
    __syncthreads();
    {
        int tc = t & 31, tp = t >> 5;
        ushort_t* xtb = xt + ((size_t)b * HW + p0) * C + c0;
#pragma unroll
        for (int i = 0; i < 64; i += 8) {
            int p = tp + i;
            float a  = tile[2 * tc][p];
            float bb = tile[2 * tc + 1][p];
            __hip_bfloat162 h2 = __float22bfloat162_rn(make_float2(a, bb));
            uint_t u;
            __builtin_memcpy(&u, &h2, 4);
            *reinterpret_cast<uint_t*>(&xtb[(size_t)p * C + 2 * tc]) = u;
        }
    }
}

// ---------------- Kernel 2: w_dcn (O, C, KK) fp32 -> Bp[kk][o][c] bf16
__global__ __launch_bounds__(256) void prep_b_k(
    const float* __restrict__ wd, ushort_t* __restrict__ bp)
{
    int idx = blockIdx.x * 256 + threadIdx.x;
    int kk = idx / (O * C);
    int r = idx - kk * O * C;
    int o = r >> 8, c = r & 255;
    float v = wd[((size_t)o * C + c) * KK + kk];
    __hip_bfloat16 hh = __float2bfloat16(v);
    ushort_t u;
    __builtin_memcpy(&u, &hh, 2);
    bp[idx] = u;
}

// ---------------- Kernel 3: w_off (27, C, 3, 3) fp32 -> bo[n=32][kk][c] bf16
__global__ __launch_bounds__(256) void prep_bo_k(
    const float* __restrict__ wo, ushort_t* __restrict__ bo)
{
    int idx = blockIdx.x * 256 + threadIdx.x;
    int n = idx / (KK * C);
    int r = idx - n * KK * C;
    int kk = r >> 8, c = r & 255;
    float v = (n < 27) ? wo[((size_t)n * C + c) * KK + kk] : 0.0f;
    __hip_bfloat16 hh = __float2bfloat16(v);
    ushort_t u;
    __builtin_memcpy(&u, &hh, 2);
    bo[idx] = u;
}

// ---------------- Kernel 4: offset conv via MFMA (XCD-swizzled, branch-free loads)
__global__ __launch_bounds__(256) void offset_mfma_k(
    const ushort_t* __restrict__ xt, const ushort_t* __restrict__ bo,
    const float* __restrict__ b_off, float* __restrict__ om)
{
    int t = threadIdx.x;
    int wv = t >> 6, l = t & 63;
    int ln = l & 15, lq = l >> 4;
    int d = blockIdx.x;                      // 576 = 8 XCD * 72 (one batch each)
    int lb = (d & 7) * 72 + (d >> 3);
    int p0 = lb * 128;
    int b = p0 / HW;
    int rem0w = p0 - b * HW + wv * 32;
    const ushort_t* xtb = xt + (size_t)b * HW * C;

    int hh0[2], ww0[2];
#pragma unroll
    for (int mt = 0; mt < 2; ++mt) {
        int rem = rem0w + mt * 16 + ln;
        hh0[mt] = rem / W;
        ww0[mt] = rem - hh0[mt] * W;
    }

    float4v acc[2][2];
#pragma unroll
    for (int i = 0; i < 2; ++i)
#pragma unroll
        for (int j = 0; j < 2; ++j) acc[i][j] = (float4v){0.f, 0.f, 0.f, 0.f};

#pragma unroll
    for (int kk = 0; kk < KK; ++kk) {
        int dy = kk / 3 - 1, dx = kk % 3 - 1;
        const ushort_t* ap[2];
        uint_t msk[2];
#pragma unroll
        for (int mt = 0; mt < 2; ++mt) {
            int hh = hh0[mt] + dy, ww = ww0[mt] + dx;
            bool ok = (hh >= 0) & (hh < H) & (ww >= 0) & (ww < W);
            msk[mt] = ok ? 0xffffffffu : 0u;
            int hc = min(max(hh, 0), H - 1);
            int wc = min(max(ww, 0), W - 1);
            ap[mt] = xtb + (size_t)(hc * W + wc) * C + lq * 8;
        }
        const ushort_t* bp0 = bo + ((size_t)(0 * 16 + ln) * KK + kk) * C + lq * 8;
        const ushort_t* bp1 = bo + ((size_t)(1 * 16 + ln) * KK + kk) * C + lq * 8;
#pragma unroll
        for (int cc = 0; cc < 8; ++cc) {
            int c0 = cc * 32;
            short8 af[2];
#pragma unroll
            for (int mt = 0; mt < 2; ++mt) {
                uint4 u = *(const uint4*)(ap[mt] + c0);
                u.x &= msk[mt]; u.y &= msk[mt]; u.z &= msk[mt]; u.w &= msk[mt];
                __builtin_memcpy(&af[mt], &u, 16);
            }
            short8 bf0 = *(const short8*)(bp0 + c0);
            short8 bf1 = *(const short8*)(bp1 + c0);
#pragma unroll
            for (int mt = 0; mt < 2; ++mt) {
                acc[mt][0] = __builtin_amdgcn_mfma_f32_16x16x32_bf16(af[mt], bf0, acc[mt][0], 0, 0, 0);
                acc[mt][1] = __builtin_amdgcn_mfma_f32_16x16x32_bf16(af[mt], bf1, acc[mt][1], 0, 0, 0);
            }
        }
    }

    float* omb = om + (size_t)b * 27 * HW + rem0w;
#pragma unroll
    for (int nt = 0; nt < 2; ++nt) {
        int oc = nt * 16 + ln;
        if (oc < 27) {
            float bv = b_off[oc];
            float* po = omb + (size_t)oc * HW + lq * 4;
#pragma unroll
            for (int mt = 0; mt < 2; ++mt) {
                float4 v;
                v.x = acc[mt][nt].x + bv;
                v.y = acc[mt][nt].y + bv;
                v.z = acc[mt][nt].z + bv;
                v.w = acc[mt][nt].w + bv;
                *(float4*)(po + mt * 16) = v;
            }
        }
    }
}

__device__ __forceinline__ float2v up2(uint_t u) {
    float2v r;
    r.x = __uint_as_float(u << 16);
    r.y = __uint_as_float(u & 0xffff0000u);
    return r;
}

__device__ __forceinline__ uint_t packbf2(float a, float b) {
    __hip_bfloat162 h2 = __float22bfloat162_rn(make_float2(a, b));
    uint_t u;
    __builtin_memcpy(&u, &h2, 4);
    return u;
}

// ---------------- Kernel 5: deformable conv main
// 512 threads = TWO independent 64-px groups (g = t>>8), each running the
// round-2 structure byte-for-byte: 4 waves (nt quarter each), 18 half-phases,
// per-chunk {stage-loads | B-prefetch(ci+1) | 16 MFMA | combine}, dbuf s_a.
// Why: round-2 counters show ~2.7 GB of L2-hit reads in 250us (~31% of L2 peak)
// with only ~8 waves/CU -> memory-latency x parallelism limited (Little's law
// needs ~27 outstanding reqs/wave at 8 waves). 16 waves/CU doubles MLP, and the
// two groups share each B phase-slice (total B traffic halves).
// Round-1 lesson: NO min-waves launch_bounds arg (VGPR quantizes to 64 -> spills).
// Round-3 lesson: never drop B-prefetch / thin out per-chunk MFMA cover.
// LDS: s_rec 128*9*12 = 13824 + s_a 2*2*4*64*32*2 = 65536 -> 79360 B -> 2 blk/CU.
__global__ __launch_bounds__(512) void dcn_main_k(
    const ushort_t* __restrict__ xt, const float* __restrict__ om,
    const ushort_t* __restrict__ bp, const float* __restrict__ b_dcn,
    const float* __restrict__ gamma, const float* __restrict__ beta,
    const float* __restrict__ rmean, const float* __restrict__ rvar,
    float* __restrict__ out)
{
    // rec: .x = px0 | (px1<<16)  (pixel indices, <HW fits 14 bits)
    //      .y = half2(row0f, row1f)   .z = half2(wA, wB)   (rank-1 weights)
    __shared__ uint3    s_rec[128 * KK];             // 13824B
    __shared__ ushort_t s_a[2][2][4][64][32];        // [buf][grp][ci][m][c] 65536B

    int t = threadIdx.x;
    int d = blockIdx.x;                          // 576 = 8 XCD * 72
    int lb = (d & 7) * 72 + (d >> 3);
    int p0 = lb * 128;
    int b = p0 / HW;
    int rem0 = p0 - b * HW;

    // ---- bilinear records, indexed [kk*128 + m], m = 0..127
    for (int v = t; v < 128 * KK; v += 512) {
        int m = v & 127;
        int k = v >> 7;
        int rem = rem0 + m;
        int h = rem / W;
        int w = rem - h * W;
        const float* omb = om + (size_t)b * 27 * HW + rem;
        float offy = omb[(size_t)(2 * k) * HW];
        float offx = omb[(size_t)(2 * k + 1) * HW];
        float z    = omb[(size_t)(18 + k) * HW];
        float mval = 1.0f / (1.0f + __expf(-z));
        float py = (float)(h + k / 3 - 1) + offy;
        float px = (float)(w + k % 3 - 1) + offx;
        float fy = floorf(py), fx = floorf(px);
        int y0 = (int)fy, x0 = (int)fx;
        float wy = py - fy, wx = px - fx;
        float row0f = (1.0f - wy) * mval * ((y0 >= 0 && y0 < H) ? 1.0f : 0.0f);
        float row1f = wy * mval * ((y0 >= -1 && y0 < H - 1) ? 1.0f : 0.0f);
        int xsel = min(max(x0, 0), W - 2);
        float wxa = (x0 >= 0 && x0 < W) ? (1.0f - wx) : 0.0f;
        float wxb = (x0 >= -1 && x0 < W - 1) ? wx : 0.0f;
        int cx0 = min(max(x0, 0), W - 1);
        int cx1 = min(max(x0 + 1, 0), W - 1);
        float wA = ((cx0 == xsel) ? wxa : 0.0f) + ((cx1 == xsel) ? wxb : 0.0f);
        float wB = ((cx0 == xsel + 1) ? wxa : 0.0f) + ((cx1 == xsel + 1) ? wxb : 0.0f);
        int yc0 = min(max(y0, 0), H - 1);
        int yc1 = min(max(y0 + 1, 0), H - 1);
        uint3 rr;
        rr.x = (uint_t)(yc0 * W + xsel) | ((uint_t)(yc1 * W + xsel) << 16);
        __half2 h01 = __floats2half2_rn(row0f, row1f);
        __half2 hAB = __floats2half2_rn(wA, wB);
        __builtin_memcpy(&rr.y, &h01, 4);
        __builtin_memcpy(&rr.z, &hAB, 4);
        s_rec[v] = rr;
    }

    float4v acc[4][4];
#pragma unroll
    for (int i = 0; i < 4; ++i)
#pragma unroll
        for (int j = 0; j < 4; ++j)
            acc[i][j] = (float4v){0.f, 0.f, 0.f, 0.f};

    const ushort_t* xtb = xt + (size_t)b * HW * C;
    int g  = t >> 8;          // 64-px group (pixel base g*64)
    int tl = t & 255;         // lane within group (round-2 roles)
    int l  = t & 63;
    int ln = l & 15;
    int lq = l >> 4;
    int wv = (t >> 6) & 3;    // wave within group -> n block (wv*64)
    int sm = tl >> 2;         // staging pixel 0..63 within group
    int sc = (tl & 3) * 8;    // staging channel octet
    int ma = g * 64 + sm;     // absolute staging pixel 0..127

    __syncthreads();

    // decode a 12B record into staging pointers (at channel base cb) + 4 weights
#define DECREC(rr_, cb_, a0_, a1_, Wt_) do {                                \
        int px0_ = (rr_).x & 0xffff;                                        \
        int px1_ = (rr_).x >> 16;                                           \
        (a0_) = xtb + (size_t)px0_ * C + (cb_) + sc;                        \
        (a1_) = xtb + (size_t)px1_ * C + (cb_) + sc;                        \
        __half2 h01_, hAB_;                                                 \
        __builtin_memcpy(&h01_, &(rr_).y, 4);                               \
        __builtin_memcpy(&hAB_, &(rr_).z, 4);                               \
        float r0_ = __low2float(h01_), r1_ = __high2float(h01_);            \
        float wa_ = __low2float(hAB_), wb_ = __high2float(hAB_);            \
        (Wt_)[0] = r0_ * wa_; (Wt_)[1] = r0_ * wb_;                         \
        (Wt_)[2] = r1_ * wa_; (Wt_)[3] = r1_ * wb_;                         \
    } while (0)

    // combine one 8-channel group from 4 corner uint4s -> packed bf16 uint4
#define COMBINE(L0_, L1_, L2_, L3_, W_, dst_) do {                          \
        uint4 pk_;                                                          \
        float2v r0_ = up2((L0_).x) * (W_)[0] + up2((L1_).x) * (W_)[1]       \
                    + up2((L2_).x) * (W_)[2] + up2((L3_).x) * (W_)[3];      \
        float2v r1_ = up2((L0_).y) * (W_)[0] + up2((L1_).y) * (W_)[1]       \
                    + up2((L2_).y) * (W_)[2] + up2((L3_).y) * (W_)[3];      \
        float2v r2_ = up2((L0_).z) * (W_)[0] + up2((L1_).z) * (W_)[1]       \
                    + up2((L2_).z) * (W_)[2] + up2((L3_).z) * (W_)[3];      \
        float2v r3_ = up2((L0_).w) * (W_)[0] + up2((L1_).w) * (W_)[1]       \
                    + up2((L2_).w) * (W_)[2] + up2((L3_).w) * (W_)[3];      \
        pk_.x = packbf2(r0_.x, r0_.y);                                      \
        pk_.y = packbf2(r1_.x, r1_.y);                                      \
        pk_.z = packbf2(r2_.x, r2_.y);                                      \
        pk_.w = packbf2(r3_.x, r3_.y);                                      \
        *(uint4*)(dst_) = pk_;                                              \
    } while (0)

    // ---- prologue: stage phase 0 (tap 0, channel-half 0) into buf 0
    {
        uint3 rr = s_rec[ma];
        const ushort_t *a0, *a1;
        float Wt[4];
        DECREC(rr, 0, a0, a1, Wt);
#pragma unroll
        for (int ci = 0; ci < 4; ++ci) {
            uint4 L0 = *(const uint4*)(a0 + ci * 32);
            uint4 L1 = *(const uint4*)(a0 + ci * 32 + C);
            uint4 L2 = *(const uint4*)(a1 + ci * 32);
            uint4 L3 = *(const uint4*)(a1 + ci * 32 + C);
            COMBINE(L0, L1, L2, L3, Wt, &s_a[0][g][ci][sm][sc]);
        }
    }
    __syncthreads();

    for (int ph = 0; ph < 2 * KK; ++ph) {
        int rb = ph & 1;
        int wb = rb ^ 1;
        bool more = (ph < 2 * KK - 1);
        int tap = ph >> 1, hf = ph & 1;

        // next-phase staging pointers/weights
        const ushort_t* a0n = xtb;
        const ushort_t* a1n = xtb;
        float Wn[4] = {0.f, 0.f, 0.f, 0.f};
        if (more) {
            int np = ph + 1;
            uint3 rr = s_rec[(np >> 1) * 128 + ma];
            DECREC(rr, (np & 1) * 128, a0n, a1n, Wn);
        }

        const ushort_t* bpk = bp + ((size_t)tap * O + wv * 64 + ln) * C + hf * 128 + lq * 8;
        short8 bfr[4], bfrN[4];
#pragma unroll
        for (int nt = 0; nt < 4; ++nt)
            bfr[nt] = *(const short8*)(bpk + (size_t)nt * 16 * C);   // chunk 0

#pragma unroll
        for (int ci = 0; ci < 4; ++ci) {
            // stage-loads for next phase, chunk ci (in flight across MFMA below)
            uint4 L0, L1, L2, L3;
            if (more) {
                L0 = *(const uint4*)(a0n + ci * 32);
                L1 = *(const uint4*)(a0n + ci * 32 + C);
                L2 = *(const uint4*)(a1n + ci * 32);
                L3 = *(const uint4*)(a1n + ci * 32 + C);
            }
            // B prefetch for chunk ci+1
            if (ci < 3) {
#pragma unroll
                for (int nt = 0; nt < 4; ++nt)
                    bfrN[nt] = *(const short8*)(bpk + (size_t)nt * 16 * C + (ci + 1) * 32);
            }
            // MFMA on current buffer, chunk ci
            short8 af[4];
#pragma unroll
            for (int mt = 0; mt < 4; ++mt)
                af[mt] = *(const short8*)&s_a[rb][g][ci][mt * 16 + ln][lq * 8];
#pragma unroll
            for (int mt = 0; mt < 4; ++mt)
#pragma unroll
                for (int nt = 0; nt < 4; ++nt)
                    acc[mt][nt] = __builtin_amdgcn_mfma_f32_16x16x32_bf16(
                        af[mt], bfr[nt], acc[mt][nt], 0, 0, 0);
            // combine + publish next phase chunk
            if (more)
                COMBINE(L0, L1, L2, L3, Wn, &s_a[wb][g][ci][sm][sc]);
#pragma unroll
            for (int nt = 0; nt < 4; ++nt)
                bfr[nt] = bfrN[nt];
        }
        __syncthreads();
    }
#undef COMBINE
#undef DECREC

    // ---- epilogue: bias + BN + ReLU
#pragma unroll
    for (int nt = 0; nt < 4; ++nt) {
        int o = wv * 64 + nt * 16 + ln;
        float scale = gamma[o] * rsqrtf(rvar[o] + EPS);
        float shift = (b_dcn[o] - rmean[o]) * scale + beta[o];
        float* po = out + ((size_t)b * O + o) * HW + rem0 + g * 64 + lq * 4;
#pragma unroll
        for (int mt = 0; mt < 4; ++mt) {
            float4 vv;
            vv.x = fmaxf(acc[mt][nt].x * scale + shift, 0.0f);
            vv.y = fmaxf(acc[mt][nt].y * scale + shift, 0.0f);
            vv.z = fmaxf(acc[mt][nt].z * scale + shift, 0.0f);
            vv.w = fmaxf(acc[mt][nt].w * scale + shift, 0.0f);
            *(float4*)(po + mt * 16) = vv;
        }
    }
}

extern "C" void kernel_launch(void* const* d_in, const int* in_sizes, int n_in,
                              void* d_out, int out_size, void* d_ws, size_t ws_size,
                              hipStream_t stream) {
    const float* x     = (const float*)d_in[0];
    const float* w_off = (const float*)d_in[1];
    const float* b_off = (const float*)d_in[2];
    const float* w_dcn = (const float*)d_in[3];
    const float* b_dcn = (const float*)d_in[4];
    const float* gamma = (const float*)d_in[5];
    const float* beta  = (const float*)d_in[6];
    const float* rmean = (const float*)d_in[7];
    const float* rvar  = (const float*)d_in[8];
    float* out = (float*)d_out;

    float*    om  = (float*)d_ws;                          // 1,990,656 f (7.96 MB)
    ushort_t* bpw = (ushort_t*)(om + (size_t)B * 27 * HW); // 589,824 us (1.18 MB)
    ushort_t* bow = bpw + (size_t)KK * O * C;              // 73,728 us (147 KB)
    ushort_t* xtw = bow + (size_t)32 * KK * C;             // 18,874,368 us (37.7 MB)

    hipLaunchKernelGGL(transpose_x_k, dim3(144, 4, 8), dim3(256), 0, stream,
                       x, xtw);
    hipLaunchKernelGGL(prep_b_k, dim3(2304), dim3(256), 0, stream,
                       w_dcn, bpw);
    hipLaunchKernelGGL(prep_bo_k, dim3(288), dim3(256), 0, stream,
                       w_off, bow);
    hipLaunchKernelGGL(offset_mfma_k, dim3(73728 / 128), dim3(256), 0, stream,
                       xtw, bow, b_off, om);
    hipLaunchKernelGGL(dcn_main_k, dim3(73728 / 128), dim3(512), 0, stream,
                       xtw, om, bpw, b_dcn, gamma, beta, rmean, rvar, out);
}

// Round 5
// 488.992 us; speedup vs baseline: 1.2654x; 1.0780x over previous
//
#include <hip/hip_runtime.h>
#include <hip/hip_bf16.h>
#include <hip/hip_fp16.h>
#include <cstdint>
#include <cstddef>

#define H 96
#define W 96
#define HW 9216
#define C 256
#define B 8
#define O 256
#define KK 9
#define EPS 1e-5f

typedef __attribute__((ext_vector_type(8))) short short8;
typedef __attribute__((ext_vector_type(4))) float float4v;
typedef __attribute__((ext_vector_type(2))) float float2v;
typedef unsigned short ushort_t;
typedef unsigned int uint_t;

// ---------------- Kernel 1: transpose x (B,C,HW) fp32 -> x_t (B,HW,C) bf16
__global__ __launch_bounds__(256) void transpose_x_k(
    const float* __restrict__ x, ushort_t* __restrict__ xt)
{
    __shared__ float tile[64][65];
    int t = threadIdx.x;
    int p0 = blockIdx.x * 64;
    int c0 = blockIdx.y * 64;
    int b  = blockIdx.z;
    {
        int tx = t & 63, ty = t >> 6;
        const float* xb = x + ((size_t)b * C + c0 + ty) * HW + p0 + tx;
#pragma unroll
        for (int i = 0; i < 64; i += 4)
            tile[ty + i][tx] = xb[(size_t)i * HW];
    }
    __syncthreads();
    {
        int tc = t & 31, tp = t >> 5;
        ushort_t* xtb = xt + ((size_t)b * HW + p0) * C + c0;
#pragma unroll
        for (int i = 0; i < 64; i += 8) {
            int p = tp + i;
            float a  = tile[2 * tc][p];
            float bb = tile[2 * tc + 1][p];
            __hip_bfloat162 h2 = __float22bfloat162_rn(make_float2(a, bb));
            uint_t u;
            __builtin_memcpy(&u, &h2, 4);
            *reinterpret_cast<uint_t*>(&xtb[(size_t)p * C + 2 * tc]) = u;
        }
    }
}

// ---------------- Kernel 2: merged weight prep (one launch instead of two)
// region 1: w_dcn (O, C, KK) fp32 -> Bp[kk][o][c] bf16   (KK*O*C elems)
// region 2: w_off (27, C, 3, 3) fp32 -> bo[n=32][kk][c] bf16 (32*KK*C elems)
__global__ __launch_bounds__(256) void prep_w_k(
    const float* __restrict__ wd, const float* __restrict__ wo,
    ushort_t* __restrict__ bp, ushort_t* __restrict__ bo)
{
    int idx = blockIdx.x * 256 + threadIdx.x;
    if (idx < KK * O * C) {
        int kk = idx / (O * C);
        int r = idx - kk * O * C;
        int o = r >> 8, c = r & 255;
        float v = wd[((size_t)o * C + c) * KK + kk];
        __hip_bfloat16 hh = __float2bfloat16(v);
        ushort_t u;
        __builtin_memcpy(&u, &hh, 2);
        bp[idx] = u;
    } else {
        int j = idx - KK * O * C;                 // j < 32*KK*C
        int n = j / (KK * C);
        int r = j - n * KK * C;
        int kk = r >> 8, c = r & 255;
        float v = (n < 27) ? wo[((size_t)n * C + c) * KK + kk] : 0.0f;
        __hip_bfloat16 hh = __float2bfloat16(v);
        ushort_t u;
        __builtin_memcpy(&u, &hh, 2);
        bo[j] = u;
    }
}

// ---------------- Kernel 3: offset conv via MFMA
// Round-5: 64 px/block (grid 1152), 16 px/wave -> 4608 waves (was 2304).
// This kernel is latency-bound with no LDS chain; low VGPR -> the extra
// waves/SIMD (2.25 -> 4.5) convert directly to latency hiding.
__global__ __launch_bounds__(256) void offset_mfma_k(
    const ushort_t* __restrict__ xt, const ushort_t* __restrict__ bo,
    const float* __restrict__ b_off, float* __restrict__ om)
{
    int t = threadIdx.x;
    int wv = t >> 6, l = t & 63;
    int ln = l & 15, lq = l >> 4;
    int d = blockIdx.x;                      // 1152 = 8 XCD * 144 (one image each)
    int lb = (d & 7) * 144 + (d >> 3);
    int p0 = lb * 64;
    int b = p0 / HW;
    int rem0w = p0 - b * HW + wv * 16;
    const ushort_t* xtb = xt + (size_t)b * HW * C;

    int rem = rem0w + ln;
    int hh0 = rem / W;
    int ww0 = rem - hh0 * W;

    float4v acc[2];
    acc[0] = (float4v){0.f, 0.f, 0.f, 0.f};
    acc[1] = (float4v){0.f, 0.f, 0.f, 0.f};

#pragma unroll
    for (int kk = 0; kk < KK; ++kk) {
        int dy = kk / 3 - 1, dx = kk % 3 - 1;
        int hh = hh0 + dy, ww = ww0 + dx;
        bool ok = (hh >= 0) & (hh < H) & (ww >= 0) & (ww < W);
        uint_t msk = ok ? 0xffffffffu : 0u;
        int hc = min(max(hh, 0), H - 1);
        int wc = min(max(ww, 0), W - 1);
        const ushort_t* ap = xtb + (size_t)(hc * W + wc) * C + lq * 8;
        const ushort_t* bp0 = bo + ((size_t)(0 * 16 + ln) * KK + kk) * C + lq * 8;
        const ushort_t* bp1 = bo + ((size_t)(1 * 16 + ln) * KK + kk) * C + lq * 8;
#pragma unroll
        for (int cc = 0; cc < 8; ++cc) {
            int c0 = cc * 32;
            uint4 u = *(const uint4*)(ap + c0);
            u.x &= msk; u.y &= msk; u.z &= msk; u.w &= msk;
            short8 af;
            __builtin_memcpy(&af, &u, 16);
            short8 bf0 = *(const short8*)(bp0 + c0);
            short8 bf1 = *(const short8*)(bp1 + c0);
            acc[0] = __builtin_amdgcn_mfma_f32_16x16x32_bf16(af, bf0, acc[0], 0, 0, 0);
            acc[1] = __builtin_amdgcn_mfma_f32_16x16x32_bf16(af, bf1, acc[1], 0, 0, 0);
        }
    }

    float* omb = om + (size_t)b * 27 * HW + rem0w;
#pragma unroll
    for (int nt = 0; nt < 2; ++nt) {
        int oc = nt * 16 + ln;
        if (oc < 27) {
            float bv = b_off[oc];
            float* po = omb + (size_t)oc * HW + lq * 4;
            float4 v;
            v.x = acc[nt].x + bv;
            v.y = acc[nt].y + bv;
            v.z = acc[nt].z + bv;
            v.w = acc[nt].w + bv;
            *(float4*)po = v;
        }
    }
}

__device__ __forceinline__ float2v up2(uint_t u) {
    float2v r;
    r.x = __uint_as_float(u << 16);
    r.y = __uint_as_float(u & 0xffff0000u);
    return r;
}

__device__ __forceinline__ uint_t packbf2(float a, float b) {
    __hip_bfloat162 h2 = __float22bfloat162_rn(make_float2(a, b));
    uint_t u;
    __builtin_memcpy(&u, &h2, 4);
    return u;
}

// ---------------- Kernel 5: deformable conv main (round-2 exact, 250us known)
// 18 half-phases (tap kk = ph>>1, channel-half hf = ph&1, 128 ch each).
// dbuf 2x16KB, packed 12B bilinear records -> LDS 39680B.
// Round-1 lesson: NO min-waves arg (VGPR quantizes to 64 -> 1.3GB spills).
// Round-3 lesson: never drop B-prefetch / thin per-chunk MFMA cover.
// Round-4 lesson: unified VGPR+AGPR file (92+64=156/lane) caps 3 waves/SIMD;
// 8-wave blocks then fit only ONE block/CU -> occupancy moves must fit 156*2.
__global__ __launch_bounds__(256) void dcn_main_k(
    const ushort_t* __restrict__ xt, const float* __restrict__ om,
    const ushort_t* __restrict__ bp, const float* __restrict__ b_dcn,
    const float* __restrict__ gamma, const float* __restrict__ beta,
    const float* __restrict__ rmean, const float* __restrict__ rvar,
    float* __restrict__ out)
{
    // rec: .x = px0 | (px1<<16)  (pixel indices, <HW fits 14 bits)
    //      .y = half2(row0f, row1f)   .z = half2(wA, wB)   (rank-1 weights)
    __shared__ uint3    s_rec[64 * KK];          // 6912B
    __shared__ ushort_t s_a[2][4][64][32];       // [buf][ci][m][c]  32768B

    int t = threadIdx.x;
    int d = blockIdx.x;                          // 1152 = 8 XCD * 144
    int lb = (d & 7) * 144 + (d >> 3);
    int p0 = lb * 64;
    int b = p0 / HW;
    int rem0 = p0 - b * HW;

    // ---- bilinear records, indexed [kk*64 + m]
    for (int v = t; v < 64 * KK; v += 256) {
        int m = v & 63;
        int k = v >> 6;
        int rem = rem0 + m;
        int h = rem / W;
        int w = rem - h * W;
        const float* omb = om + (size_t)b * 27 * HW + rem;
        float offy = omb[(size_t)(2 * k) * HW];
        float offx = omb[(size_t)(2 * k + 1) * HW];
        float z    = omb[(size_t)(18 + k) * HW];
        float mval = 1.0f / (1.0f + __expf(-z));
        float py = (float)(h + k / 3 - 1) + offy;
        float px = (float)(w + k % 3 - 1) + offx;
        float fy = floorf(py), fx = floorf(px);
        int y0 = (int)fy, x0 = (int)fx;
        float wy = py - fy, wx = px - fx;
        float row0f = (1.0f - wy) * mval * ((y0 >= 0 && y0 < H) ? 1.0f : 0.0f);
        float row1f = wy * mval * ((y0 >= -1 && y0 < H - 1) ? 1.0f : 0.0f);
        int xsel = min(max(x0, 0), W - 2);
        float wxa = (x0 >= 0 && x0 < W) ? (1.0f - wx) : 0.0f;
        float wxb = (x0 >= -1 && x0 < W - 1) ? wx : 0.0f;
        int cx0 = min(max(x0, 0), W - 1);
        int cx1 = min(max(x0 + 1, 0), W - 1);
        float wA = ((cx0 == xsel) ? wxa : 0.0f) + ((cx1 == xsel) ? wxb : 0.0f);
        float wB = ((cx0 == xsel + 1) ? wxa : 0.0f) + ((cx1 == xsel + 1) ? wxb : 0.0f);
        int yc0 = min(max(y0, 0), H - 1);
        int yc1 = min(max(y0 + 1, 0), H - 1);
        uint3 rr;
        rr.x = (uint_t)(yc0 * W + xsel) | ((uint_t)(yc1 * W + xsel) << 16);
        __half2 h01 = __floats2half2_rn(row0f, row1f);
        __half2 hAB = __floats2half2_rn(wA, wB);
        __builtin_memcpy(&rr.y, &h01, 4);
        __builtin_memcpy(&rr.z, &hAB, 4);
        s_rec[v] = rr;
    }

    float4v acc[4][4];
#pragma unroll
    for (int i = 0; i < 4; ++i)
#pragma unroll
        for (int j = 0; j < 4; ++j)
            acc[i][j] = (float4v){0.f, 0.f, 0.f, 0.f};

    const ushort_t* xtb = xt + (size_t)b * HW * C;
    int wv = t >> 6;          // wave -> n block (wv*64)
    int l  = t & 63;
    int ln = l & 15;
    int lq = l >> 4;
    int sm = t >> 2;          // staging pixel 0..63
    int sc = (t & 3) * 8;     // staging channel octet

    __syncthreads();

    // decode a 12B record into staging pointers (at channel base cb) + 4 weights
#define DECREC(rr_, cb_, a0_, a1_, Wt_) do {                                \
        int px0_ = (rr_).x & 0xffff;                                        \
        int px1_ = (rr_).x >> 16;                                           \
        (a0_) = xtb + (size_t)px0_ * C + (cb_) + sc;                        \
        (a1_) = xtb + (size_t)px1_ * C + (cb_) + sc;                        \
        __half2 h01_, hAB_;                                                 \
        __builtin_memcpy(&h01_, &(rr_).y, 4);                               \
        __builtin_memcpy(&hAB_, &(rr_).z, 4);                               \
        float r0_ = __low2float(h01_), r1_ = __high2float(h01_);            \
        float wa_ = __low2float(hAB_), wb_ = __high2float(hAB_);            \
        (Wt_)[0] = r0_ * wa_; (Wt_)[1] = r0_ * wb_;                         \
        (Wt_)[2] = r1_ * wa_; (Wt_)[3] = r1_ * wb_;                         \
    } while (0)

    // combine one 8-channel group from 4 corner uint4s -> packed bf16 uint4
#define COMBINE(L0_, L1_, L2_, L3_, W_, dst_) do {                          \
        uint4 pk_;                                                          \
        float2v r0_ = up2((L0_).x) * (W_)[0] + up2((L1_).x) * (W_)[1]       \
                    + up2((L2_).x) * (W_)[2] + up2((L3_).x) * (W_)[3];      \
        float2v r1_ = up2((L0_).y) * (W_)[0] + up2((L1_).y) * (W_)[1]       \
                    + up2((L2_).y) * (W_)[2] + up2((L3_).y) * (W_)[3];      \
        float2v r2_ = up2((L0_).z) * (W_)[0] + up2((L1_).z) * (W_)[1]       \
                    + up2((L2_).z) * (W_)[2] + up2((L3_).z) * (W_)[3];      \
        float2v r3_ = up2((L0_).w) * (W_)[0] + up2((L1_).w) * (W_)[1]       \
                    + up2((L2_).w) * (W_)[2] + up2((L3_).w) * (W_)[3];      \
        pk_.x = packbf2(r0_.x, r0_.y);                                      \
        pk_.y = packbf2(r1_.x, r1_.y);                                      \
        pk_.z = packbf2(r2_.x, r2_.y);                                      \
        pk_.w = packbf2(r3_.x, r3_.y);                                      \
        *(uint4*)(dst_) = pk_;                                              \
    } while (0)

    // ---- prologue: stage phase 0 (tap 0, channel-half 0) into buf 0
    {
        uint3 rr = s_rec[sm];
        const ushort_t *a0, *a1;
        float Wt[4];
        DECREC(rr, 0, a0, a1, Wt);
#pragma unroll
        for (int ci = 0; ci < 4; ++ci) {
            uint4 L0 = *(const uint4*)(a0 + ci * 32);
            uint4 L1 = *(const uint4*)(a0 + ci * 32 + C);
            uint4 L2 = *(const uint4*)(a1 + ci * 32);
            uint4 L3 = *(const uint4*)(a1 + ci * 32 + C);
            COMBINE(L0, L1, L2, L3, Wt, &s_a[0][ci][sm][sc]);
        }
    }
    __syncthreads();

    for (int ph = 0; ph < 2 * KK; ++ph) {
        int rb = ph & 1;
        int wb = rb ^ 1;
        bool more = (ph < 2 * KK - 1);
        int tap = ph >> 1, hf = ph & 1;

        // next-phase staging pointers/weights
        const ushort_t* a0n = xtb;
        const ushort_t* a1n = xtb;
        float Wn[4] = {0.f, 0.f, 0.f, 0.f};
        if (more) {
            int np = ph + 1;
            uint3 rr = s_rec[(np >> 1) * 64 + sm];
            DECREC(rr, (np & 1) * 128, a0n, a1n, Wn);
        }

        const ushort_t* bpk = bp + ((size_t)tap * O + wv * 64 + ln) * C + hf * 128 + lq * 8;
        short8 bfr[4], bfrN[4];
#pragma unroll
        for (int nt = 0; nt < 4; ++nt)
            bfr[nt] = *(const short8*)(bpk + (size_t)nt * 16 * C);   // chunk 0

#pragma unroll
        for (int ci = 0; ci < 4; ++ci) {
            // stage-loads for next phase, chunk ci (in flight across MFMA below)
            uint4 L0, L1, L2, L3;
            if (more) {
                L0 = *(const uint4*)(a0n + ci * 32);
                L1 = *(const uint4*)(a0n + ci * 32 + C);
                L2 = *(const uint4*)(a1n + ci * 32);
                L3 = *(const uint4*)(a1n + ci * 32 + C);
            }
            // B prefetch for chunk ci+1
            if (ci < 3) {
#pragma unroll
                for (int nt = 0; nt < 4; ++nt)
                    bfrN[nt] = *(const short8*)(bpk + (size_t)nt * 16 * C + (ci + 1) * 32);
            }
            // MFMA on current buffer, chunk ci
            short8 af[4];
#pragma unroll
            for (int mt = 0; mt < 4; ++mt)
                af[mt] = *(const short8*)&s_a[rb][ci][mt * 16 + ln][lq * 8];
#pragma unroll
            for (int mt = 0; mt < 4; ++mt)
#pragma unroll
                for (int nt = 0; nt < 4; ++nt)
                    acc[mt][nt] = __builtin_amdgcn_mfma_f32_16x16x32_bf16(
                        af[mt], bfr[nt], acc[mt][nt], 0, 0, 0);
            // combine + publish next phase chunk
            if (more)
                COMBINE(L0, L1, L2, L3, Wn, &s_a[wb][ci][sm][sc]);
#pragma unroll
            for (int nt = 0; nt < 4; ++nt)
                bfr[nt] = bfrN[nt];
        }
        __syncthreads();
    }
#undef COMBINE
#undef DECREC

    // ---- epilogue: bias + BN + ReLU
#pragma unroll
    for (int nt = 0; nt < 4; ++nt) {
        int o = wv * 64 + nt * 16 + ln;
        float scale = gamma[o] * rsqrtf(rvar[o] + EPS);
        float shift = (b_dcn[o] - rmean[o]) * scale + beta[o];
        float* po = out + ((size_t)b * O + o) * HW + rem0 + lq * 4;
#pragma unroll
        for (int mt = 0; mt < 4; ++mt) {
            float4 vv;
            vv.x = fmaxf(acc[mt][nt].x * scale + shift, 0.0f);
            vv.y = fmaxf(acc[mt][nt].y * scale + shift, 0.0f);
            vv.z = fmaxf(acc[mt][nt].z * scale + shift, 0.0f);
            vv.w = fmaxf(acc[mt][nt].w * scale + shift, 0.0f);
            *(float4*)(po + mt * 16) = vv;
        }
    }
}

extern "C" void kernel_launch(void* const* d_in, const int* in_sizes, int n_in,
                              void* d_out, int out_size, void* d_ws, size_t ws_size,
                              hipStream_t stream) {
    const float* x     = (const float*)d_in[0];
    const float* w_off = (const float*)d_in[1];
    const float* b_off = (const float*)d_in[2];
    const float* w_dcn = (const float*)d_in[3];
    const float* b_dcn = (const float*)d_in[4];
    const float* gamma = (const float*)d_in[5];
    const float* beta  = (const float*)d_in[6];
    const float* rmean = (const float*)d_in[7];
    const float* rvar  = (const float*)d_in[8];
    float* out = (float*)d_out;

    float*    om  = (float*)d_ws;                          // 1,990,656 f (7.96 MB)
    ushort_t* bpw = (ushort_t*)(om + (size_t)B * 27 * HW); // 589,824 us (1.18 MB)
    ushort_t* bow = bpw + (size_t)KK * O * C;              // 73,728 us (147 KB)
    ushort_t* xtw = bow + (size_t)32 * KK * C;             // 18,874,368 us (37.7 MB)

    hipLaunchKernelGGL(transpose_x_k, dim3(144, 4, 8), dim3(256), 0, stream,
                       x, xtw);
    hipLaunchKernelGGL(prep_w_k, dim3((KK * O * C + 32 * KK * C) / 256), dim3(256),
                       0, stream, w_dcn, w_off, bpw, bow);
    hipLaunchKernelGGL(offset_mfma_k, dim3(73728 / 64), dim3(256), 0, stream,
                       xtw, bow, b_off, om);
    hipLaunchKernelGGL(dcn_main_k, dim3(73728 / 64), dim3(256), 0, stream,
                       xtw, om, bpw, b_dcn, gamma, beta, rmean, rvar, out);
}

// Round 6
// 465.350 us; speedup vs baseline: 1.3297x; 1.0508x over previous
//
#include <hip/hip_runtime.h>
#include <hip/hip_bf16.h>
#include <hip/hip_fp16.h>
#include <cstdint>
#include <cstddef>

#define H 96
#define W 96
#define HW 9216
#define C 256
#define B 8
#define O 256
#define KK 9
#define EPS 1e-5f

typedef __attribute__((ext_vector_type(8))) short short8;
typedef __attribute__((ext_vector_type(4))) float float4v;
typedef __attribute__((ext_vector_type(2))) float float2v;
typedef unsigned short ushort_t;
typedef unsigned int uint_t;

// ---------------- Kernel 1: transpose x (B,C,HW) fp32 -> x_t (B,HW,C) bf16
__global__ __launch_bounds__(256) void transpose_x_k(
    const float* __restrict__ x, ushort_t* __restrict__ xt)
{
    __shared__ float tile[64][65];
    int t = threadIdx.x;
    int p0 = blockIdx.x * 64;
    int c0 = blockIdx.y * 64;
    int b  = blockIdx.z;
    {
        int tx = t & 63, ty = t >> 6;
        const float* xb = x + ((size_t)b * C + c0 + ty) * HW + p0 + tx;
#pragma unroll
        for (int i = 0; i < 64; i += 4)
            tile[ty + i][tx] = xb[(size_t)i * HW];
    }
    __syncthreads();
    {
        int tc = t & 31, tp = t >> 5;
        ushort_t* xtb = xt + ((size_t)b * HW + p0) * C + c0;
#pragma unroll
        for (int i = 0; i < 64; i += 8) {
            int p = tp + i;
            float a  = tile[2 * tc][p];
            float bb = tile[2 * tc + 1][p];
            __hip_bfloat162 h2 = __float22bfloat162_rn(make_float2(a, bb));
            uint_t u;
            __builtin_memcpy(&u, &h2, 4);
            *reinterpret_cast<uint_t*>(&xtb[(size_t)p * C + 2 * tc]) = u;
        }
    }
}

// ---------------- Kernel 2: merged weight prep (one launch instead of two)
__global__ __launch_bounds__(256) void prep_w_k(
    const float* __restrict__ wd, const float* __restrict__ wo,
    ushort_t* __restrict__ bp, ushort_t* __restrict__ bo)
{
    int idx = blockIdx.x * 256 + threadIdx.x;
    if (idx < KK * O * C) {
        int kk = idx / (O * C);
        int r = idx - kk * O * C;
        int o = r >> 8, c = r & 255;
        float v = wd[((size_t)o * C + c) * KK + kk];
        __hip_bfloat16 hh = __float2bfloat16(v);
        ushort_t u;
        __builtin_memcpy(&u, &hh, 2);
        bp[idx] = u;
    } else {
        int j = idx - KK * O * C;                 // j < 32*KK*C
        int n = j / (KK * C);
        int r = j - n * KK * C;
        int kk = r >> 8, c = r & 255;
        float v = (n < 27) ? wo[((size_t)n * C + c) * KK + kk] : 0.0f;
        __hip_bfloat16 hh = __float2bfloat16(v);
        ushort_t u;
        __builtin_memcpy(&u, &hh, 2);
        bo[j] = u;
    }
}

// ---------------- Kernel 3: offset conv via MFMA (round-2 exact: 128px/block,
// 2 pixel-tiles/wave -> 4 MFMAs/chunk of latency cover; grid 576).
// Round-5 lesson: halving per-wave MFMA cover to buy waves regresses (+20us).
__global__ __launch_bounds__(256) void offset_mfma_k(
    const ushort_t* __restrict__ xt, const ushort_t* __restrict__ bo,
    const float* __restrict__ b_off, float* __restrict__ om)
{
    int t = threadIdx.x;
    int wv = t >> 6, l = t & 63;
    int ln = l & 15, lq = l >> 4;
    int d = blockIdx.x;                      // 576 = 8 XCD * 72 (one batch each)
    int lb = (d & 7) * 72 + (d >> 3);
    int p0 = lb * 128;
    int b = p0 / HW;
    int rem0w = p0 - b * HW + wv * 32;
    const ushort_t* xtb = xt + (size_t)b * HW * C;

    int hh0[2], ww0[2];
#pragma unroll
    for (int mt = 0; mt < 2; ++mt) {
        int rem = rem0w + mt * 16 + ln;
        hh0[mt] = rem / W;
        ww0[mt] = rem - hh0[mt] * W;
    }

    float4v acc[2][2];
#pragma unroll
    for (int i = 0; i < 2; ++i)
#pragma unroll
        for (int j = 0; j < 2; ++j) acc[i][j] = (float4v){0.f, 0.f, 0.f, 0.f};

#pragma unroll
    for (int kk = 0; kk < KK; ++kk) {
        int dy = kk / 3 - 1, dx = kk % 3 - 1;
        const ushort_t* ap[2];
        uint_t msk[2];
#pragma unroll
        for (int mt = 0; mt < 2; ++mt) {
            int hh = hh0[mt] + dy, ww = ww0[mt] + dx;
            bool ok = (hh >= 0) & (hh < H) & (ww >= 0) & (ww < W);
            msk[mt] = ok ? 0xffffffffu : 0u;
            int hc = min(max(hh, 0), H - 1);
            int wc = min(max(ww, 0), W - 1);
            ap[mt] = xtb + (size_t)(hc * W + wc) * C + lq * 8;
        }
        const ushort_t* bp0 = bo + ((size_t)(0 * 16 + ln) * KK + kk) * C + lq * 8;
        const ushort_t* bp1 = bo + ((size_t)(1 * 16 + ln) * KK + kk) * C + lq * 8;
#pragma unroll
        for (int cc = 0; cc < 8; ++cc) {
            int c0 = cc * 32;
            short8 af[2];
#pragma unroll
            for (int mt = 0; mt < 2; ++mt) {
                uint4 u = *(const uint4*)(ap[mt] + c0);
                u.x &= msk[mt]; u.y &= msk[mt]; u.z &= msk[mt]; u.w &= msk[mt];
                __builtin_memcpy(&af[mt], &u, 16);
            }
            short8 bf0 = *(const short8*)(bp0 + c0);
            short8 bf1 = *(const short8*)(bp1 + c0);
#pragma unroll
            for (int mt = 0; mt < 2; ++mt) {
                acc[mt][0] = __builtin_amdgcn_mfma_f32_16x16x32_bf16(af[mt], bf0, acc[mt][0], 0, 0, 0);
                acc[mt][1] = __builtin_amdgcn_mfma_f32_16x16x32_bf16(af[mt], bf1, acc[mt][1], 0, 0, 0);
            }
        }
    }

    float* omb = om + (size_t)b * 27 * HW + rem0w;
#pragma unroll
    for (int nt = 0; nt < 2; ++nt) {
        int oc = nt * 16 + ln;
        if (oc < 27) {
            float bv = b_off[oc];
            float* po = omb + (size_t)oc * HW + lq * 4;
#pragma unroll
            for (int mt = 0; mt < 2; ++mt) {
                float4 v;
                v.x = acc[mt][nt].x + bv;
                v.y = acc[mt][nt].y + bv;
                v.z = acc[mt][nt].z + bv;
                v.w = acc[mt][nt].w + bv;
                *(float4*)(po + mt * 16) = v;
            }
        }
    }
}

__device__ __forceinline__ float2v up2(uint_t u) {
    float2v r;
    r.x = __uint_as_float(u << 16);
    r.y = __uint_as_float(u & 0xffff0000u);
    return r;
}

__device__ __forceinline__ uint_t packbf2(float a, float b) {
    __hip_bfloat162 h2 = __float22bfloat162_rn(make_float2(a, b));
    uint_t u;
    __builtin_memcpy(&u, &h2, 4);
    return u;
}

// ---------------- Kernel 5: deformable conv main (round-2 structure +
// LDS XOR swizzle on s_a).
// s_a row stride = 64B -> fragment reads (ln varies, lq fixed) hit 2 banks
// = 8-way conflict (SQ_LDS_BANK_CONFLICT 5.3M/dispatch). Fix: swizzle the
// 16B slot index with the row: slot' = slot ^ ((m>>1)&3), i.e.
// c' = c ^ ((m&6)<<2). Applied on BOTH combine-write and fragment-read
// (global-load addresses stay linear). Both sides become <=2-way (free).
// Round-1 lesson: NO min-waves launch_bounds arg (VGPR quantizes -> spills).
// Round-3/5 lesson: never thin per-chunk MFMA cover / B-prefetch.
// Round-4 lesson: unified VGPR+AGPR file (92+64) caps 3 waves/SIMD.
__global__ __launch_bounds__(256) void dcn_main_k(
    const ushort_t* __restrict__ xt, const float* __restrict__ om,
    const ushort_t* __restrict__ bp, const float* __restrict__ b_dcn,
    const float* __restrict__ gamma, const float* __restrict__ beta,
    const float* __restrict__ rmean, const float* __restrict__ rvar,
    float* __restrict__ out)
{
    // rec: .x = px0 | (px1<<16)  (pixel indices, <HW fits 14 bits)
    //      .y = half2(row0f, row1f)   .z = half2(wA, wB)   (rank-1 weights)
    __shared__ uint3    s_rec[64 * KK];          // 6912B
    __shared__ ushort_t s_a[2][4][64][32];       // [buf][ci][m][c]  32768B

    int t = threadIdx.x;
    int d = blockIdx.x;                          // 1152 = 8 XCD * 144
    int lb = (d & 7) * 144 + (d >> 3);
    int p0 = lb * 64;
    int b = p0 / HW;
    int rem0 = p0 - b * HW;

    // ---- bilinear records, indexed [kk*64 + m]
    for (int v = t; v < 64 * KK; v += 256) {
        int m = v & 63;
        int k = v >> 6;
        int rem = rem0 + m;
        int h = rem / W;
        int w = rem - h * W;
        const float* omb = om + (size_t)b * 27 * HW + rem;
        float offy = omb[(size_t)(2 * k) * HW];
        float offx = omb[(size_t)(2 * k + 1) * HW];
        float z    = omb[(size_t)(18 + k) * HW];
        float mval = 1.0f / (1.0f + __expf(-z));
        float py = (float)(h + k / 3 - 1) + offy;
        float px = (float)(w + k % 3 - 1) + offx;
        float fy = floorf(py), fx = floorf(px);
        int y0 = (int)fy, x0 = (int)fx;
        float wy = py - fy, wx = px - fx;
        float row0f = (1.0f - wy) * mval * ((y0 >= 0 && y0 < H) ? 1.0f : 0.0f);
        float row1f = wy * mval * ((y0 >= -1 && y0 < H - 1) ? 1.0f : 0.0f);
        int xsel = min(max(x0, 0), W - 2);
        float wxa = (x0 >= 0 && x0 < W) ? (1.0f - wx) : 0.0f;
        float wxb = (x0 >= -1 && x0 < W - 1) ? wx : 0.0f;
        int cx0 = min(max(x0, 0), W - 1);
        int cx1 = min(max(x0 + 1, 0), W - 1);
        float wA = ((cx0 == xsel) ? wxa : 0.0f) + ((cx1 == xsel) ? wxb : 0.0f);
        float wB = ((cx0 == xsel + 1) ? wxa : 0.0f) + ((cx1 == xsel + 1) ? wxb : 0.0f);
        int yc0 = min(max(y0, 0), H - 1);
        int yc1 = min(max(y0 + 1, 0), H - 1);
        uint3 rr;
        rr.x = (uint_t)(yc0 * W + xsel) | ((uint_t)(yc1 * W + xsel) << 16);
        __half2 h01 = __floats2half2_rn(row0f, row1f);
        __half2 hAB = __floats2half2_rn(wA, wB);
        __builtin_memcpy(&rr.y, &h01, 4);
        __builtin_memcpy(&rr.z, &hAB, 4);
        s_rec[v] = rr;
    }

    float4v acc[4][4];
#pragma unroll
    for (int i = 0; i < 4; ++i)
#pragma unroll
        for (int j = 0; j < 4; ++j)
            acc[i][j] = (float4v){0.f, 0.f, 0.f, 0.f};

    const ushort_t* xtb = xt + (size_t)b * HW * C;
    int wv = t >> 6;          // wave -> n block (wv*64)
    int l  = t & 63;
    int ln = l & 15;
    int lq = l >> 4;
    int sm = t >> 2;          // staging pixel 0..63
    int sc = (t & 3) * 8;     // staging channel octet (GLOBAL side, linear)
    int scw = sc ^ ((sm & 6) << 2);        // LDS write slot, swizzled
    int lqw = (lq * 8) ^ ((ln & 6) << 2);  // LDS read slot, swizzled

    __syncthreads();

    // decode a 12B record into staging pointers (at channel base cb) + 4 weights
#define DECREC(rr_, cb_, a0_, a1_, Wt_) do {                                \
        int px0_ = (rr_).x & 0xffff;                                        \
        int px1_ = (rr_).x >> 16;                                           \
        (a0_) = xtb + (size_t)px0_ * C + (cb_) + sc;                        \
        (a1_) = xtb + (size_t)px1_ * C + (cb_) + sc;                        \
        __half2 h01_, hAB_;                                                 \
        __builtin_memcpy(&h01_, &(rr_).y, 4);                               \
        __builtin_memcpy(&hAB_, &(rr_).z, 4);                               \
        float r0_ = __low2float(h01_), r1_ = __high2float(h01_);            \
        float wa_ = __low2float(hAB_), wb_ = __high2float(hAB_);            \
        (Wt_)[0] = r0_ * wa_; (Wt_)[1] = r0_ * wb_;                         \
        (Wt_)[2] = r1_ * wa_; (Wt_)[3] = r1_ * wb_;                         \
    } while (0)

    // combine one 8-channel group from 4 corner uint4s -> packed bf16 uint4
#define COMBINE(L0_, L1_, L2_, L3_, W_, dst_) do {                          \
        uint4 pk_;                                                          \
        float2v r0_ = up2((L0_).x) * (W_)[0] + up2((L1_).x) * (W_)[1]       \
                    + up2((L2_).x) * (W_)[2] + up2((L3_).x) * (W_)[3];      \
        float2v r1_ = up2((L0_).y) * (W_)[0] + up2((L1_).y) * (W_)[1]       \
                    + up2((L2_).y) * (W_)[2] + up2((L3_).y) * (W_)[3];      \
        float2v r2_ = up2((L0_).z) * (W_)[0] + up2((L1_).z) * (W_)[1]       \
                    + up2((L2_).z) * (W_)[2] + up2((L3_).z) * (W_)[3];      \
        float2v r3_ = up2((L0_).w) * (W_)[0] + up2((L1_).w) * (W_)[1]       \
                    + up2((L2_).w) * (W_)[2] + up2((L3_).w) * (W_)[3];      \
        pk_.x = packbf2(r0_.x, r0_.y);                                      \
        pk_.y = packbf2(r1_.x, r1_.y);                                      \
        pk_.z = packbf2(r2_.x, r2_.y);                                      \
        pk_.w = packbf2(r3_.x, r3_.y);                                      \
        *(uint4*)(dst_) = pk_;                                              \
    } while (0)

    // ---- prologue: stage phase 0 (tap 0, channel-half 0) into buf 0
    {
        uint3 rr = s_rec[sm];
        const ushort_t *a0, *a1;
        float Wt[4];
        DECREC(rr, 0, a0, a1, Wt);
#pragma unroll
        for (int ci = 0; ci < 4; ++ci) {
            uint4 L0 = *(const uint4*)(a0 + ci * 32);
            uint4 L1 = *(const uint4*)(a0 + ci * 32 + C);
            uint4 L2 = *(const uint4*)(a1 + ci * 32);
            uint4 L3 = *(const uint4*)(a1 + ci * 32 + C);
            COMBINE(L0, L1, L2, L3, Wt, &s_a[0][ci][sm][scw]);
        }
    }
    __syncthreads();

    for (int ph = 0; ph < 2 * KK; ++ph) {
        int rb = ph & 1;
        int wb = rb ^ 1;
        bool more = (ph < 2 * KK - 1);
        int tap = ph >> 1, hf = ph & 1;

        // next-phase staging pointers/weights
        const ushort_t* a0n = xtb;
        const ushort_t* a1n = xtb;
        float Wn[4] = {0.f, 0.f, 0.f, 0.f};
        if (more) {
            int np = ph + 1;
            uint3 rr = s_rec[(np >> 1) * 64 + sm];
            DECREC(rr, (np & 1) * 128, a0n, a1n, Wn);
        }

        const ushort_t* bpk = bp + ((size_t)tap * O + wv * 64 + ln) * C + hf * 128 + lq * 8;
        short8 bfr[4], bfrN[4];
#pragma unroll
        for (int nt = 0; nt < 4; ++nt)
            bfr[nt] = *(const short8*)(bpk + (size_t)nt * 16 * C);   // chunk 0

#pragma unroll
        for (int ci = 0; ci < 4; ++ci) {
            // stage-loads for next phase, chunk ci (in flight across MFMA below)
            uint4 L0, L1, L2, L3;
            if (more) {
                L0 = *(const uint4*)(a0n + ci * 32);
                L1 = *(const uint4*)(a0n + ci * 32 + C);
                L2 = *(const uint4*)(a1n + ci * 32);
                L3 = *(const uint4*)(a1n + ci * 32 + C);
            }
            // B prefetch for chunk ci+1
            if (ci < 3) {
#pragma unroll
                for (int nt = 0; nt < 4; ++nt)
                    bfrN[nt] = *(const short8*)(bpk + (size_t)nt * 16 * C + (ci + 1) * 32);
            }
            // MFMA on current buffer, chunk ci (swizzled fragment reads)
            short8 af[4];
#pragma unroll
            for (int mt = 0; mt < 4; ++mt)
                af[mt] = *(const short8*)&s_a[rb][ci][mt * 16 + ln][lqw];
#pragma unroll
            for (int mt = 0; mt < 4; ++mt)
#pragma unroll
                for (int nt = 0; nt < 4; ++nt)
                    acc[mt][nt] = __builtin_amdgcn_mfma_f32_16x16x32_bf16(
                        af[mt], bfr[nt], acc[mt][nt], 0, 0, 0);
            // combine + publish next phase chunk (swizzled write)
            if (more)
                COMBINE(L0, L1, L2, L3, Wn, &s_a[wb][ci][sm][scw]);
#pragma unroll
            for (int nt = 0; nt < 4; ++nt)
                bfr[nt] = bfrN[nt];
        }
        __syncthreads();
    }
#undef COMBINE
#undef DECREC

    // ---- epilogue: bias + BN + ReLU
#pragma unroll
    for (int nt = 0; nt < 4; ++nt) {
        int o = wv * 64 + nt * 16 + ln;
        float scale = gamma[o] * rsqrtf(rvar[o] + EPS);
        float shift = (b_dcn[o] - rmean[o]) * scale + beta[o];
        float* po = out + ((size_t)b * O + o) * HW + rem0 + lq * 4;
#pragma unroll
        for (int mt = 0; mt < 4; ++mt) {
            float4 vv;
            vv.x = fmaxf(acc[mt][nt].x * scale + shift, 0.0f);
            vv.y = fmaxf(acc[mt][nt].y * scale + shift, 0.0f);
            vv.z = fmaxf(acc[mt][nt].z * scale + shift, 0.0f);
            vv.w = fmaxf(acc[mt][nt].w * scale + shift, 0.0f);
            *(float4*)(po + mt * 16) = vv;
        }
    }
}

extern "C" void kernel_launch(void* const* d_in, const int* in_sizes, int n_in,
                              void* d_out, int out_size, void* d_ws, size_t ws_size,
                              hipStream_t stream) {
    const float* x     = (const float*)d_in[0];
    const float* w_off = (const float*)d_in[1];
    const float* b_off = (const float*)d_in[2];
    const float* w_dcn = (const float*)d_in[3];
    const float* b_dcn = (const float*)d_in[4];
    const float* gamma = (const float*)d_in[5];
    const float* beta  = (const float*)d_in[6];
    const float* rmean = (const float*)d_in[7];
    const float* rvar  = (const float*)d_in[8];
    float* out = (float*)d_out;

    float*    om  = (float*)d_ws;                          // 1,990,656 f (7.96 MB)
    ushort_t* bpw = (ushort_t*)(om + (size_t)B * 27 * HW); // 589,824 us (1.18 MB)
    ushort_t* bow = bpw + (size_t)KK * O * C;              // 73,728 us (147 KB)
    ushort_t* xtw = bow + (size_t)32 * KK * C;              // 18,874,368 us (37.7 MB)

    hipLaunchKernelGGL(transpose_x_k, dim3(144, 4, 8), dim3(256), 0, stream,
                       x, xtw);
    hipLaunchKernelGGL(prep_w_k, dim3((KK * O * C + 32 * KK * C) / 256), dim3(256),
                       0, stream, w_dcn, w_off, bpw, bow);
    hipLaunchKernelGGL(offset_mfma_k, dim3(73728 / 128), dim3(256), 0, stream,
                       xtw, bow, b_off, om);
    hipLaunchKernelGGL(dcn_main_k, dim3(73728 / 64), dim3(256), 0, stream,
                       xtw, om, bpw, b_dcn, gamma, beta, rmean, rvar, out);
}